// Round 3
// baseline (8299.673 us; speedup 1.0000x reference)
//
#include <hip/hip_runtime.h>
#include <cstddef>

// B=2 T=512 D=512 V=256 MEM=256 ; M = B*T = 1024
// All inputs fp32 (x is int32); all outputs fp32.
#define F_ELUQK 1
#define F_CAUSAL 2
#define F_DIV 4
#define F_NN 8
#define F_SCALE 16
#define GRU_WGS 64

// ---------- ws layout (float units) ----------
enum : int {
  OFF_SIN = 0,                         // [1024][512]
  OFF_GI = 524288,                     // [1024][1536]
  OFF_COMB = OFF_GI + 1572864,         // [1024][2048]  p_f | intent | l_mem | episodes
  OFF_PS = OFF_COMB + 2097152,         // [1024][512]
  OFF_QKV = OFF_PS + 524288,           // [1024][1536]  q(elu+1) | k(elu+1) | v
  OFF_SCORES = OFF_QKV + 1572864,      // [1024][512]
  OFF_DEN = OFF_SCORES + 524288,       // [1024]
  OFF_TMP = OFF_DEN + 1024,            // [1024][512]
  OFF_ATTN = OFF_TMP + 524288,         // [1024][256]
  OFF_SW = OFF_ATTN + 262144,          // [256][512]
  OFF_HBUF = OFF_SW + 131072,          // [2][1024]
  OFF_CTR = OFF_HBUF + 2048
};

__global__ __launch_bounds__(256) void embed_kernel(const float* __restrict__ soma,
                                                    const int* __restrict__ x,
                                                    float* __restrict__ sin_) {
  int g = blockIdx.x * 256 + threadIdx.x;     // < 524288
  int m = g >> 9, d = g & 511;
  sin_[g] = soma[(size_t)x[m] * 512 + d];
}

// ---------- generic tiled GEMM:  C[m, coff+n] = sum_k A[m,k] * B(n,k)  (+epilogue) ----------
// NT: B(n,k) = B[(n + rowoff)*ldb + k] ; NN: B(n,k) = B[(k + rowoff)*ldb + n]
__global__ __launch_bounds__(256) void gemm(
    const float* __restrict__ A, int lda, const float* __restrict__ B, int ldb,
    float* __restrict__ C, int ldc, int coff, int K,
    const float* __restrict__ bias, const float* __restrict__ den,
    float scale, int flags, int bBatch) {
  __shared__ float As[16 * 65];
  __shared__ float Bs[16 * 65];
  int tid = threadIdx.x;
  int n0 = blockIdx.x * 64, m0 = blockIdx.y * 64;
  int rowoff = (m0 >> 9) * bBatch;
  int tx = tid & 15, ty = tid >> 4;

  if ((flags & F_CAUSAL) && n0 > ((m0 & 511) + 63)) {
    #pragma unroll
    for (int i = 0; i < 4; ++i)
      #pragma unroll
      for (int j = 0; j < 4; ++j)
        C[(size_t)(m0 + ty * 4 + i) * ldc + coff + n0 + tx * 4 + j] = 0.f;
    return;
  }

  float acc[4][4] = {};
  for (int k0 = 0; k0 < K; k0 += 16) {
    {
      int rr = tid >> 2, c4 = (tid & 3) << 2;
      const float* ap = A + (size_t)(m0 + rr) * lda + (k0 + c4);
      float4 av = *(const float4*)ap;
      As[(c4 + 0) * 65 + rr] = av.x;
      As[(c4 + 1) * 65 + rr] = av.y;
      As[(c4 + 2) * 65 + rr] = av.z;
      As[(c4 + 3) * 65 + rr] = av.w;
    }
    if (!(flags & F_NN)) {
      int rr = tid >> 2, c4 = (tid & 3) << 2;
      const float* bp = B + (size_t)(n0 + rr + rowoff) * ldb + (k0 + c4);
      float4 bv = *(const float4*)bp;
      Bs[(c4 + 0) * 65 + rr] = bv.x; Bs[(c4 + 1) * 65 + rr] = bv.y;
      Bs[(c4 + 2) * 65 + rr] = bv.z; Bs[(c4 + 3) * 65 + rr] = bv.w;
    } else {
      int kk = tid >> 4, n4 = (tid & 15) << 2;
      const float* bp = B + (size_t)(k0 + kk + rowoff) * ldb + (n0 + n4);
      float4 bv = *(const float4*)bp;
      Bs[kk * 65 + n4 + 0] = bv.x; Bs[kk * 65 + n4 + 1] = bv.y;
      Bs[kk * 65 + n4 + 2] = bv.z; Bs[kk * 65 + n4 + 3] = bv.w;
    }
    __syncthreads();
    #pragma unroll
    for (int k = 0; k < 16; ++k) {
      float av[4], bv[4];
      #pragma unroll
      for (int i = 0; i < 4; ++i) av[i] = As[k * 65 + ty * 4 + i];
      #pragma unroll
      for (int j = 0; j < 4; ++j) bv[j] = Bs[k * 65 + tx * 4 + j];
      #pragma unroll
      for (int i = 0; i < 4; ++i)
        #pragma unroll
        for (int j = 0; j < 4; ++j)
          acc[i][j] = fmaf(av[i], bv[j], acc[i][j]);
    }
    __syncthreads();
  }
  #pragma unroll
  for (int i = 0; i < 4; ++i) {
    int m = m0 + ty * 4 + i;
    float dv = (flags & F_DIV) ? (1.0f / (den[m] + 1e-6f)) : 1.0f;
    #pragma unroll
    for (int j = 0; j < 4; ++j) {
      int n = n0 + tx * 4 + j;
      float v = acc[i][j];
      if (bias) v += bias[n];
      if (flags & F_ELUQK) { if (n < 1024) v = (v > 0.f) ? (v + 1.f) : __expf(v); }
      if (flags & F_CAUSAL) { if (n > (m & 511)) v = 0.f; }
      if (flags & F_SCALE) v *= scale;
      if (flags & F_DIV) v *= dv;
      C[(size_t)m * ldc + coff + n] = v;
    }
  }
}

// ---------- persistent multi-WG GRU scan ----------
// WG k owns hidden units j in [k*8,(k+1)*8): whh rows {j, j+512, j+1024} in LDS fp32.
// Per step: broadcast h via global double buffer + device-scope spin barrier.
__global__ __launch_bounds__(256) void gru_kernel(
    const float* __restrict__ gi,      // [1024][1536]  (m = b*512+t)
    const float* __restrict__ whh,     // [1536][512]
    const float* __restrict__ bhh,     // [1536]
    const float* __restrict__ h0,      // [2*512]
    float* __restrict__ p_out, int ldp,
    float* __restrict__ hT_out,        // 2*512
    float* __restrict__ hbuf,          // [2][1024]
    unsigned int* __restrict__ ctr) {
  __shared__ float wl[24 * 516];
  __shared__ float hl[1024];
  __shared__ float P[48];
  __shared__ float bl[24];
  int tid = threadIdx.x, wg = blockIdx.x, j0 = wg * 8;

  for (int q = tid; q < 3072; q += 256) {        // 24*512/4
    int r = q >> 7, c4 = (q & 127) << 2;
    int row = (r >> 3) * 512 + j0 + (r & 7);
    float4 v = *(const float4*)(whh + (size_t)row * 512 + c4);
    wl[r * 516 + c4 + 0] = v.x; wl[r * 516 + c4 + 1] = v.y;
    wl[r * 516 + c4 + 2] = v.z; wl[r * 516 + c4 + 3] = v.w;
  }
  if (tid < 24) bl[tid] = bhh[(tid >> 3) * 512 + j0 + (tid & 7)];

  int part = tid & 7, r = tid >> 3;
  for (int t = 0; t < 512; ++t) {
    float i_r = 0.f, i_z = 0.f, i_n = 0.f;
    const float* hsrc = (t == 0) ? h0 : (hbuf + (size_t)(t & 1) * 1024);
    for (int idx = tid; idx < 1024; idx += 256) hl[idx] = hsrc[idx];
    if (tid < 16) {  // prefetch gi for gate phase
      int b = tid >> 3, jl = tid & 7;
      const float* girow = gi + (size_t)(b * 512 + t) * 1536 + j0 + jl;
      i_r = girow[0]; i_z = girow[512]; i_n = girow[1024];
    }
    __syncthreads();
    if (r < 24) {
      const float* wr = wl + r * 516;
      float a0 = 0.f, a1 = 0.f;
      #pragma unroll 8
      for (int i = 0; i < 32; ++i) {
        int c = (i << 4) + (part << 1);
        float2 w = *(const float2*)(wr + c);
        float2 ha = *(const float2*)(hl + c);
        float2 hb = *(const float2*)(hl + 512 + c);
        a0 += w.x * ha.x + w.y * ha.y;
        a1 += w.x * hb.x + w.y * hb.y;
      }
      a0 += __shfl_xor(a0, 1); a0 += __shfl_xor(a0, 2); a0 += __shfl_xor(a0, 4);
      a1 += __shfl_xor(a1, 1); a1 += __shfl_xor(a1, 2); a1 += __shfl_xor(a1, 4);
      if (part == 0) { P[r] = a0; P[24 + r] = a1; }
    }
    __syncthreads();
    if (tid < 16) {
      int b = tid >> 3, jl = tid & 7, j = j0 + jl;
      float gh_r = P[b * 24 + jl] + bl[jl];
      float gh_z = P[b * 24 + 8 + jl] + bl[8 + jl];
      float gh_n = P[b * 24 + 16 + jl] + bl[16 + jl];
      float hold = hl[b * 512 + j];
      float rg = 1.0f / (1.0f + __expf(-(i_r + gh_r)));
      float zg = 1.0f / (1.0f + __expf(-(i_z + gh_z)));
      float ng = tanhf(i_n + rg * gh_n);
      float hnew = (1.0f - zg) * ng + zg * hold;
      hbuf[(size_t)((t + 1) & 1) * 1024 + b * 512 + j] = hnew;
      p_out[(size_t)(b * 512 + t) * ldp + j] = hnew;
      if (t == 511) hT_out[b * 512 + j] = hnew;
    }
    __syncthreads();
    if (tid == 0) {
      __threadfence();
      __hip_atomic_fetch_add(ctr, 1u, __ATOMIC_RELEASE, __HIP_MEMORY_SCOPE_AGENT);
      unsigned target = (unsigned)GRU_WGS * (unsigned)(t + 1);
      while (__hip_atomic_load(ctr, __ATOMIC_ACQUIRE, __HIP_MEMORY_SCOPE_AGENT) < target)
        __builtin_amdgcn_s_sleep(8);
      __threadfence();
    }
    __syncthreads();
  }
}

// ---------- row reductions ----------
__global__ __launch_bounds__(256) void rowsum_kernel(const float* __restrict__ S,
                                                     float* __restrict__ den) {
  int m = blockIdx.x, tid = threadIdx.x;
  float s = S[(size_t)m * 512 + tid] + S[(size_t)m * 512 + 256 + tid];
  #pragma unroll
  for (int off = 32; off > 0; off >>= 1) s += __shfl_down(s, off);
  __shared__ float r4[4];
  if ((tid & 63) == 0) r4[tid >> 6] = s;
  __syncthreads();
  if (tid == 0) den[m] = r4[0] + r4[1] + r4[2] + r4[3];
}

__global__ __launch_bounds__(256) void softmax_kernel(float* __restrict__ a) {
  int m = blockIdx.x, tid = threadIdx.x;
  float v = a[(size_t)m * 256 + tid];
  float mx = v;
  #pragma unroll
  for (int off = 32; off > 0; off >>= 1) mx = fmaxf(mx, __shfl_down(mx, off));
  __shared__ float r4[4];
  __shared__ float s4[4];
  if ((tid & 63) == 0) r4[tid >> 6] = mx;
  __syncthreads();
  mx = fmaxf(fmaxf(r4[0], r4[1]), fmaxf(r4[2], r4[3]));
  float e = __expf(v - mx);
  float s = e;
  #pragma unroll
  for (int off = 32; off > 0; off >>= 1) s += __shfl_down(s, off);
  if ((tid & 63) == 0) s4[tid >> 6] = s;
  __syncthreads();
  s = s4[0] + s4[1] + s4[2] + s4[3];
  a[(size_t)m * 256 + tid] = e / s;
}

__global__ __launch_bounds__(256) void ln_kernel(
    const float* __restrict__ src, float* __restrict__ dst, int ldd, int dcoff,
    const float* __restrict__ gv, const float* __restrict__ bv, int tanhFirst) {
  int m = blockIdx.x, tid = threadIdx.x;
  float x0 = src[(size_t)m * 512 + tid];
  float x1 = src[(size_t)m * 512 + 256 + tid];
  if (tanhFirst) { x0 = tanhf(x0); x1 = tanhf(x1); }
  float s = x0 + x1, ss = x0 * x0 + x1 * x1;
  #pragma unroll
  for (int off = 32; off > 0; off >>= 1) { s += __shfl_down(s, off); ss += __shfl_down(ss, off); }
  __shared__ float rs[4], rss[4];
  if ((tid & 63) == 0) { rs[tid >> 6] = s; rss[tid >> 6] = ss; }
  __syncthreads();
  float st = rs[0] + rs[1] + rs[2] + rs[3];
  float sst = rss[0] + rss[1] + rss[2] + rss[3];
  float mean = st * (1.0f / 512.0f);
  float var = sst * (1.0f / 512.0f) - mean * mean;
  float inv = rsqrtf(var + 1e-5f);
  float y0 = (x0 - mean) * inv * gv[tid] + bv[tid];
  float y1 = (x1 - mean) * inv * gv[256 + tid] + bv[256 + tid];
  if (!tanhFirst) { y0 = tanhf(y0); y1 = tanhf(y1); }
  dst[(size_t)m * ldd + dcoff + tid] = y0;
  dst[(size_t)m * ldd + dcoff + 256 + tid] = y1;
}

__global__ __launch_bounds__(256) void swnorm_kernel(const float* __restrict__ soma,
                                                     float* __restrict__ sw) {
  int r = blockIdx.x, tid = threadIdx.x;
  float x0 = soma[(size_t)r * 512 + tid];
  float x1 = soma[(size_t)r * 512 + 256 + tid];
  float ss = x0 * x0 + x1 * x1;
  #pragma unroll
  for (int off = 32; off > 0; off >>= 1) ss += __shfl_down(ss, off);
  __shared__ float r4[4];
  if ((tid & 63) == 0) r4[tid >> 6] = ss;
  __syncthreads();
  float norm = sqrtf(r4[0] + r4[1] + r4[2] + r4[3]);
  norm = fmaxf(norm, 1e-12f);
  float inv = 1.0f / norm;
  sw[(size_t)r * 512 + tid] = x0 * inv;
  sw[(size_t)r * 512 + 256 + tid] = x1 * inv;
}

// ---------- host ----------
extern "C" void kernel_launch(void* const* d_in, const int* in_sizes, int n_in,
                              void* d_out, int out_size, void* d_ws, size_t ws_size,
                              hipStream_t stream) {
  (void)in_sizes; (void)n_in; (void)out_size; (void)ws_size;
  float* W = (float*)d_ws;
  float* outf = (float*)d_out;
  // out layout (floats): logits[262144] | thought[524288] | hf1[1024] | hs1[1024]
  const int* x = (const int*)d_in[0];
  const float* soma = (const float*)d_in[3];

  hipMemsetAsync((char*)d_ws + (size_t)OFF_CTR * 4, 0, 256, stream);

  embed_kernel<<<2048, 256, 0, stream>>>(soma, x, W + OFF_SIN);

  // gi_f = s_in @ fast_wih^T + fast_bih
  gemm<<<dim3(24, 16), 256, 0, stream>>>(W + OFF_SIN, 512, (const float*)d_in[4], 512,
      W + OFF_GI, 1536, 0, 512, (const float*)d_in[6], nullptr, 1.f, 0, 0);

  // GRU1 -> p_f into combined cols [0,512); hf1 -> out
  gru_kernel<<<GRU_WGS, 256, 0, stream>>>(W + OFF_GI, (const float*)d_in[5],
      (const float*)d_in[7], (const float*)d_in[1], W + OFF_COMB, 2048,
      outf + 786432, W + OFF_HBUF, (unsigned int*)(W + OFF_CTR));

  // gi_s = p_f @ slow_wih^T + slow_bih
  gemm<<<dim3(24, 16), 256, 0, stream>>>(W + OFF_COMB, 2048, (const float*)d_in[8], 512,
      W + OFF_GI, 1536, 0, 512, (const float*)d_in[10], nullptr, 1.f, 0, 0);

  // GRU2 -> p_s; hs1 -> out
  gru_kernel<<<GRU_WGS, 256, 0, stream>>>(W + OFF_GI, (const float*)d_in[9],
      (const float*)d_in[11], (const float*)d_in[2], W + OFF_PS, 512,
      outf + 787456, W + OFF_HBUF, (unsigned int*)(W + OFF_CTR) + 1);

  // qkv = p_s @ qkv_w^T + b ; elu+1 on q,k
  gemm<<<dim3(24, 16), 256, 0, stream>>>(W + OFF_PS, 512, (const float*)d_in[12], 512,
      W + OFF_QKV, 1536, 0, 512, (const float*)d_in[13], nullptr, 1.f, F_ELUQK, 0);

  // scores = causal(q k^T) per batch
  gemm<<<dim3(8, 16), 256, 0, stream>>>(W + OFF_QKV, 1536, W + OFF_QKV + 512, 1536,
      W + OFF_SCORES, 512, 0, 512, nullptr, nullptr, 1.f, F_CAUSAL, 512);

  rowsum_kernel<<<1024, 256, 0, stream>>>(W + OFF_SCORES, W + OFF_DEN);

  // l_mem = (scores @ v) / (den + 1e-6) -> combined cols [1024,1536)
  gemm<<<dim3(8, 16), 256, 0, stream>>>(W + OFF_SCORES, 512, W + OFF_QKV + 1024, 1536,
      W + OFF_COMB, 2048, 1024, 512, nullptr, W + OFF_DEN, 1.f, F_NN | F_DIV, 512);

  // intent = tanh(LN(p_s @ gate_w^T + gate_b)) -> combined cols [512,1024)
  gemm<<<dim3(8, 16), 256, 0, stream>>>(W + OFF_PS, 512, (const float*)d_in[14], 512,
      W + OFF_TMP, 512, 0, 512, (const float*)d_in[15], nullptr, 1.f, 0, 0);
  ln_kernel<<<1024, 256, 0, stream>>>(W + OFF_TMP, W + OFF_COMB, 2048, 512,
      (const float*)d_in[16], (const float*)d_in[17], 0);

  // hippocampus -> combined cols [1536,2048)
  gemm<<<dim3(8, 16), 256, 0, stream>>>(W + OFF_PS, 512, (const float*)d_in[19], 512,
      W + OFF_TMP, 512, 0, 512, (const float*)d_in[20], nullptr, 1.f, 0, 0);
  gemm<<<dim3(4, 16), 256, 0, stream>>>(W + OFF_TMP, 512, (const float*)d_in[18], 512,
      W + OFF_ATTN, 256, 0, 512, nullptr, nullptr, 0.04419417382415922f, F_SCALE, 0);
  softmax_kernel<<<1024, 256, 0, stream>>>(W + OFF_ATTN);
  gemm<<<dim3(8, 16), 256, 0, stream>>>(W + OFF_ATTN, 256, (const float*)d_in[18], 512,
      W + OFF_COMB, 2048, 1536, 256, nullptr, nullptr, 1.f, F_NN, 0);

  // axon + LN -> thought directly into out (fp32)
  gemm<<<dim3(8, 16), 256, 0, stream>>>(W + OFF_COMB, 2048, (const float*)d_in[21], 2048,
      W + OFF_TMP, 512, 0, 2048, (const float*)d_in[22], nullptr, 1.f, 0, 0);
  ln_kernel<<<1024, 256, 0, stream>>>(W + OFF_TMP, outf + 262144, 512, 0,
      (const float*)d_in[23], (const float*)d_in[24], 1);

  // logits = (thought @ sw^T) * 16 -> out (fp32)
  swnorm_kernel<<<256, 256, 0, stream>>>(soma, W + OFF_SW);
  gemm<<<dim3(4, 16), 256, 0, stream>>>(outf + 262144, 512, W + OFF_SW, 512,
      outf, 256, 0, 512, nullptr, nullptr, 16.f, F_SCALE, 0);
}

// Round 4
// 4923.895 us; speedup vs baseline: 1.6856x; 1.6856x over previous
//
#include <hip/hip_runtime.h>
#include <cstddef>

// B=2 T=512 D=512 V=256 MEM=256 ; M = B*T = 1024
// All inputs fp32 (x is int32); all outputs fp32.
#define F_ELUQK 1
#define F_CAUSAL 2
#define F_DIV 4
#define F_NN 8
#define F_SCALE 16
#define GRU_WGS 64

// ---------- ws layout (float units) ----------
enum : int {
  OFF_SIN = 0,                         // [1024][512]
  OFF_GI = 524288,                     // [1024][1536]
  OFF_COMB = OFF_GI + 1572864,         // [1024][2048]  p_f | intent | l_mem | episodes
  OFF_PS = OFF_COMB + 2097152,         // [1024][512]
  OFF_QKV = OFF_PS + 524288,           // [1024][1536]  q(elu+1) | k(elu+1) | v
  OFF_SCORES = OFF_QKV + 1572864,      // [1024][512]
  OFF_DEN = OFF_SCORES + 524288,       // [1024]
  OFF_TMP = OFF_DEN + 1024,            // [1024][512]
  OFF_ATTN = OFF_TMP + 524288,         // [1024][256]
  OFF_SW = OFF_ATTN + 262144,          // [256][512]
  OFF_HBUF = OFF_SW + 131072,          // [2][1024]
  OFF_CTR = OFF_HBUF + 2048
};

__global__ __launch_bounds__(256) void embed_kernel(const float* __restrict__ soma,
                                                    const int* __restrict__ x,
                                                    float* __restrict__ sin_) {
  int g = blockIdx.x * 256 + threadIdx.x;     // < 524288
  int m = g >> 9, d = g & 511;
  sin_[g] = soma[(size_t)x[m] * 512 + d];
}

// ---------- generic tiled GEMM:  C[m, coff+n] = sum_k A[m,k] * B(n,k)  (+epilogue) ----------
// NT: B(n,k) = B[(n + rowoff)*ldb + k] ; NN: B(n,k) = B[(k + rowoff)*ldb + n]
__global__ __launch_bounds__(256) void gemm(
    const float* __restrict__ A, int lda, const float* __restrict__ B, int ldb,
    float* __restrict__ C, int ldc, int coff, int K,
    const float* __restrict__ bias, const float* __restrict__ den,
    float scale, int flags, int bBatch) {
  __shared__ float As[16 * 65];
  __shared__ float Bs[16 * 65];
  int tid = threadIdx.x;
  int n0 = blockIdx.x * 64, m0 = blockIdx.y * 64;
  int rowoff = (m0 >> 9) * bBatch;
  int tx = tid & 15, ty = tid >> 4;

  if ((flags & F_CAUSAL) && n0 > ((m0 & 511) + 63)) {
    #pragma unroll
    for (int i = 0; i < 4; ++i)
      #pragma unroll
      for (int j = 0; j < 4; ++j)
        C[(size_t)(m0 + ty * 4 + i) * ldc + coff + n0 + tx * 4 + j] = 0.f;
    return;
  }

  float acc[4][4] = {};
  for (int k0 = 0; k0 < K; k0 += 16) {
    {
      int rr = tid >> 2, c4 = (tid & 3) << 2;
      const float* ap = A + (size_t)(m0 + rr) * lda + (k0 + c4);
      float4 av = *(const float4*)ap;
      As[(c4 + 0) * 65 + rr] = av.x;
      As[(c4 + 1) * 65 + rr] = av.y;
      As[(c4 + 2) * 65 + rr] = av.z;
      As[(c4 + 3) * 65 + rr] = av.w;
    }
    if (!(flags & F_NN)) {
      int rr = tid >> 2, c4 = (tid & 3) << 2;
      const float* bp = B + (size_t)(n0 + rr + rowoff) * ldb + (k0 + c4);
      float4 bv = *(const float4*)bp;
      Bs[(c4 + 0) * 65 + rr] = bv.x; Bs[(c4 + 1) * 65 + rr] = bv.y;
      Bs[(c4 + 2) * 65 + rr] = bv.z; Bs[(c4 + 3) * 65 + rr] = bv.w;
    } else {
      int kk = tid >> 4, n4 = (tid & 15) << 2;
      const float* bp = B + (size_t)(k0 + kk + rowoff) * ldb + (n0 + n4);
      float4 bv = *(const float4*)bp;
      Bs[kk * 65 + n4 + 0] = bv.x; Bs[kk * 65 + n4 + 1] = bv.y;
      Bs[kk * 65 + n4 + 2] = bv.z; Bs[kk * 65 + n4 + 3] = bv.w;
    }
    __syncthreads();
    #pragma unroll
    for (int k = 0; k < 16; ++k) {
      float av[4], bv[4];
      #pragma unroll
      for (int i = 0; i < 4; ++i) av[i] = As[k * 65 + ty * 4 + i];
      #pragma unroll
      for (int j = 0; j < 4; ++j) bv[j] = Bs[k * 65 + tx * 4 + j];
      #pragma unroll
      for (int i = 0; i < 4; ++i)
        #pragma unroll
        for (int j = 0; j < 4; ++j)
          acc[i][j] = fmaf(av[i], bv[j], acc[i][j]);
    }
    __syncthreads();
  }
  #pragma unroll
  for (int i = 0; i < 4; ++i) {
    int m = m0 + ty * 4 + i;
    float dv = (flags & F_DIV) ? (1.0f / (den[m] + 1e-6f)) : 1.0f;
    #pragma unroll
    for (int j = 0; j < 4; ++j) {
      int n = n0 + tx * 4 + j;
      float v = acc[i][j];
      if (bias) v += bias[n];
      if (flags & F_ELUQK) { if (n < 1024) v = (v > 0.f) ? (v + 1.f) : __expf(v); }
      if (flags & F_CAUSAL) { if (n > (m & 511)) v = 0.f; }
      if (flags & F_SCALE) v *= scale;
      if (flags & F_DIV) v *= dv;
      C[(size_t)m * ldc + coff + n] = v;
    }
  }
}

// ---------- persistent multi-WG GRU scan ----------
// WG k owns hidden units j in [k*8,(k+1)*8): whh rows {j, j+512, j+1024} in LDS fp32.
// Per step: h broadcast via agent-scope (sc1) atomics through global double buffer;
// spin barrier uses RELAXED agent loads (NO acquire fence -> no buffer_inv L2 nuke).
__global__ __launch_bounds__(256) void gru_kernel(
    const float* __restrict__ gi,      // [1024][1536]  (m = b*512+t)
    const float* __restrict__ whh,     // [1536][512]
    const float* __restrict__ bhh,     // [1536]
    const float* __restrict__ h0,      // [2*512]
    float* __restrict__ p_out, int ldp,
    float* __restrict__ hT_out,        // 2*512
    float* __restrict__ hbuf,          // [2][1024] floats
    unsigned int* __restrict__ ctr) {
  __shared__ float wl[24 * 516];
  __shared__ unsigned long long hlq[512];   // 1024 floats
  __shared__ float P[48];
  __shared__ float bl[24];
  float* hl = (float*)hlq;
  unsigned long long* hbq = (unsigned long long*)hbuf;
  int tid = threadIdx.x, wg = blockIdx.x, j0 = wg * 8;

  for (int q = tid; q < 3072; q += 256) {        // 24*512/4
    int r = q >> 7, c4 = (q & 127) << 2;
    int row = (r >> 3) * 512 + j0 + (r & 7);
    float4 v = *(const float4*)(whh + (size_t)row * 512 + c4);
    wl[r * 516 + c4 + 0] = v.x; wl[r * 516 + c4 + 1] = v.y;
    wl[r * 516 + c4 + 2] = v.z; wl[r * 516 + c4 + 3] = v.w;
  }
  if (tid < 24) bl[tid] = bhh[(tid >> 3) * 512 + j0 + (tid & 7)];

  int part = tid & 7, r = tid >> 3;
  for (int t = 0; t < 512; ++t) {
    float i_r = 0.f, i_z = 0.f, i_n = 0.f;
    if (t == 0) {
      const unsigned long long* h0q = (const unsigned long long*)h0;
      hlq[tid] = h0q[tid];
      hlq[256 + tid] = h0q[256 + tid];
    } else {
      int boff = (t & 1) * 512;
      hlq[tid] = __hip_atomic_load(hbq + boff + tid, __ATOMIC_RELAXED, __HIP_MEMORY_SCOPE_AGENT);
      hlq[256 + tid] = __hip_atomic_load(hbq + boff + 256 + tid, __ATOMIC_RELAXED, __HIP_MEMORY_SCOPE_AGENT);
    }
    if (tid < 16) {  // prefetch gi for gate phase
      int b = tid >> 3, jl = tid & 7;
      const float* girow = gi + (size_t)(b * 512 + t) * 1536 + j0 + jl;
      i_r = girow[0]; i_z = girow[512]; i_n = girow[1024];
    }
    __syncthreads();
    if (r < 24) {
      const float* wr = wl + r * 516;
      float a0 = 0.f, a1 = 0.f;
      #pragma unroll 8
      for (int i = 0; i < 32; ++i) {
        int c = (i << 4) + (part << 1);
        float2 w = *(const float2*)(wr + c);
        float2 ha = *(const float2*)(hl + c);
        float2 hb = *(const float2*)(hl + 512 + c);
        a0 += w.x * ha.x + w.y * ha.y;
        a1 += w.x * hb.x + w.y * hb.y;
      }
      a0 += __shfl_xor(a0, 1); a0 += __shfl_xor(a0, 2); a0 += __shfl_xor(a0, 4);
      a1 += __shfl_xor(a1, 1); a1 += __shfl_xor(a1, 2); a1 += __shfl_xor(a1, 4);
      if (part == 0) { P[r] = a0; P[24 + r] = a1; }
    }
    __syncthreads();
    if (tid < 16) {
      int b = tid >> 3, jl = tid & 7, j = j0 + jl;
      float gh_r = P[b * 24 + jl] + bl[jl];
      float gh_z = P[b * 24 + 8 + jl] + bl[8 + jl];
      float gh_n = P[b * 24 + 16 + jl] + bl[16 + jl];
      float hold = hl[b * 512 + j];
      float rg = 1.0f / (1.0f + __expf(-(i_r + gh_r)));
      float zg = 1.0f / (1.0f + __expf(-(i_z + gh_z)));
      float ng = tanhf(i_n + rg * gh_n);
      float hnew = (1.0f - zg) * ng + zg * hold;
      __hip_atomic_store(hbuf + (size_t)((t + 1) & 1) * 1024 + b * 512 + j, hnew,
                         __ATOMIC_RELAXED, __HIP_MEMORY_SCOPE_AGENT);
      p_out[(size_t)(b * 512 + t) * ldp + j] = hnew;
      if (t == 511) hT_out[b * 512 + j] = hnew;
    }
    __syncthreads();   // drains each wave's vmcnt (sc1 stores now globally visible)
    if (tid == 0) {
      __hip_atomic_fetch_add(ctr, 1u, __ATOMIC_RELEASE, __HIP_MEMORY_SCOPE_AGENT);
      unsigned target = (unsigned)GRU_WGS * (unsigned)(t + 1);
      while (__hip_atomic_load(ctr, __ATOMIC_RELAXED, __HIP_MEMORY_SCOPE_AGENT) < target)
        __builtin_amdgcn_s_sleep(1);
    }
    __syncthreads();
  }
}

// ---------- row reductions ----------
__global__ __launch_bounds__(256) void rowsum_kernel(const float* __restrict__ S,
                                                     float* __restrict__ den) {
  int m = blockIdx.x, tid = threadIdx.x;
  float s = S[(size_t)m * 512 + tid] + S[(size_t)m * 512 + 256 + tid];
  #pragma unroll
  for (int off = 32; off > 0; off >>= 1) s += __shfl_down(s, off);
  __shared__ float r4[4];
  if ((tid & 63) == 0) r4[tid >> 6] = s;
  __syncthreads();
  if (tid == 0) den[m] = r4[0] + r4[1] + r4[2] + r4[3];
}

__global__ __launch_bounds__(256) void softmax_kernel(float* __restrict__ a) {
  int m = blockIdx.x, tid = threadIdx.x;
  float v = a[(size_t)m * 256 + tid];
  float mx = v;
  #pragma unroll
  for (int off = 32; off > 0; off >>= 1) mx = fmaxf(mx, __shfl_down(mx, off));
  __shared__ float r4[4];
  __shared__ float s4[4];
  if ((tid & 63) == 0) r4[tid >> 6] = mx;
  __syncthreads();
  mx = fmaxf(fmaxf(r4[0], r4[1]), fmaxf(r4[2], r4[3]));
  float e = __expf(v - mx);
  float s = e;
  #pragma unroll
  for (int off = 32; off > 0; off >>= 1) s += __shfl_down(s, off);
  if ((tid & 63) == 0) s4[tid >> 6] = s;
  __syncthreads();
  s = s4[0] + s4[1] + s4[2] + s4[3];
  a[(size_t)m * 256 + tid] = e / s;
}

__global__ __launch_bounds__(256) void ln_kernel(
    const float* __restrict__ src, float* __restrict__ dst, int ldd, int dcoff,
    const float* __restrict__ gv, const float* __restrict__ bv, int tanhFirst) {
  int m = blockIdx.x, tid = threadIdx.x;
  float x0 = src[(size_t)m * 512 + tid];
  float x1 = src[(size_t)m * 512 + 256 + tid];
  if (tanhFirst) { x0 = tanhf(x0); x1 = tanhf(x1); }
  float s = x0 + x1, ss = x0 * x0 + x1 * x1;
  #pragma unroll
  for (int off = 32; off > 0; off >>= 1) { s += __shfl_down(s, off); ss += __shfl_down(ss, off); }
  __shared__ float rs[4], rss[4];
  if ((tid & 63) == 0) { rs[tid >> 6] = s; rss[tid >> 6] = ss; }
  __syncthreads();
  float st = rs[0] + rs[1] + rs[2] + rs[3];
  float sst = rss[0] + rss[1] + rss[2] + rss[3];
  float mean = st * (1.0f / 512.0f);
  float var = sst * (1.0f / 512.0f) - mean * mean;
  float inv = rsqrtf(var + 1e-5f);
  float y0 = (x0 - mean) * inv * gv[tid] + bv[tid];
  float y1 = (x1 - mean) * inv * gv[256 + tid] + bv[256 + tid];
  if (!tanhFirst) { y0 = tanhf(y0); y1 = tanhf(y1); }
  dst[(size_t)m * ldd + dcoff + tid] = y0;
  dst[(size_t)m * ldd + dcoff + 256 + tid] = y1;
}

__global__ __launch_bounds__(256) void swnorm_kernel(const float* __restrict__ soma,
                                                     float* __restrict__ sw) {
  int r = blockIdx.x, tid = threadIdx.x;
  float x0 = soma[(size_t)r * 512 + tid];
  float x1 = soma[(size_t)r * 512 + 256 + tid];
  float ss = x0 * x0 + x1 * x1;
  #pragma unroll
  for (int off = 32; off > 0; off >>= 1) ss += __shfl_down(ss, off);
  __shared__ float r4[4];
  if ((tid & 63) == 0) r4[tid >> 6] = ss;
  __syncthreads();
  float norm = sqrtf(r4[0] + r4[1] + r4[2] + r4[3]);
  norm = fmaxf(norm, 1e-12f);
  float inv = 1.0f / norm;
  sw[(size_t)r * 512 + tid] = x0 * inv;
  sw[(size_t)r * 512 + 256 + tid] = x1 * inv;
}

// ---------- host ----------
extern "C" void kernel_launch(void* const* d_in, const int* in_sizes, int n_in,
                              void* d_out, int out_size, void* d_ws, size_t ws_size,
                              hipStream_t stream) {
  (void)in_sizes; (void)n_in; (void)out_size; (void)ws_size;
  float* W = (float*)d_ws;
  float* outf = (float*)d_out;
  // out layout (floats): logits[262144] | thought[524288] | hf1[1024] | hs1[1024]
  const int* x = (const int*)d_in[0];
  const float* soma = (const float*)d_in[3];

  hipMemsetAsync((char*)d_ws + (size_t)OFF_CTR * 4, 0, 256, stream);

  embed_kernel<<<2048, 256, 0, stream>>>(soma, x, W + OFF_SIN);

  // gi_f = s_in @ fast_wih^T + fast_bih
  gemm<<<dim3(24, 16), 256, 0, stream>>>(W + OFF_SIN, 512, (const float*)d_in[4], 512,
      W + OFF_GI, 1536, 0, 512, (const float*)d_in[6], nullptr, 1.f, 0, 0);

  // GRU1 -> p_f into combined cols [0,512); hf1 -> out
  gru_kernel<<<GRU_WGS, 256, 0, stream>>>(W + OFF_GI, (const float*)d_in[5],
      (const float*)d_in[7], (const float*)d_in[1], W + OFF_COMB, 2048,
      outf + 786432, W + OFF_HBUF, (unsigned int*)(W + OFF_CTR));

  // gi_s = p_f @ slow_wih^T + slow_bih
  gemm<<<dim3(24, 16), 256, 0, stream>>>(W + OFF_COMB, 2048, (const float*)d_in[8], 512,
      W + OFF_GI, 1536, 0, 512, (const float*)d_in[10], nullptr, 1.f, 0, 0);

  // GRU2 -> p_s; hs1 -> out
  gru_kernel<<<GRU_WGS, 256, 0, stream>>>(W + OFF_GI, (const float*)d_in[9],
      (const float*)d_in[11], (const float*)d_in[2], W + OFF_PS, 512,
      outf + 787456, W + OFF_HBUF, (unsigned int*)(W + OFF_CTR) + 1);

  // qkv = p_s @ qkv_w^T + b ; elu+1 on q,k
  gemm<<<dim3(24, 16), 256, 0, stream>>>(W + OFF_PS, 512, (const float*)d_in[12], 512,
      W + OFF_QKV, 1536, 0, 512, (const float*)d_in[13], nullptr, 1.f, F_ELUQK, 0);

  // scores = causal(q k^T) per batch
  gemm<<<dim3(8, 16), 256, 0, stream>>>(W + OFF_QKV, 1536, W + OFF_QKV + 512, 1536,
      W + OFF_SCORES, 512, 0, 512, nullptr, nullptr, 1.f, F_CAUSAL, 512);

  rowsum_kernel<<<1024, 256, 0, stream>>>(W + OFF_SCORES, W + OFF_DEN);

  // l_mem = (scores @ v) / (den + 1e-6) -> combined cols [1024,1536)
  gemm<<<dim3(8, 16), 256, 0, stream>>>(W + OFF_SCORES, 512, W + OFF_QKV + 1024, 1536,
      W + OFF_COMB, 2048, 1024, 512, nullptr, W + OFF_DEN, 1.f, F_NN | F_DIV, 512);

  // intent = tanh(LN(p_s @ gate_w^T + gate_b)) -> combined cols [512,1024)
  gemm<<<dim3(8, 16), 256, 0, stream>>>(W + OFF_PS, 512, (const float*)d_in[14], 512,
      W + OFF_TMP, 512, 0, 512, (const float*)d_in[15], nullptr, 1.f, 0, 0);
  ln_kernel<<<1024, 256, 0, stream>>>(W + OFF_TMP, W + OFF_COMB, 2048, 512,
      (const float*)d_in[16], (const float*)d_in[17], 0);

  // hippocampus -> combined cols [1536,2048)
  gemm<<<dim3(8, 16), 256, 0, stream>>>(W + OFF_PS, 512, (const float*)d_in[19], 512,
      W + OFF_TMP, 512, 0, 512, (const float*)d_in[20], nullptr, 1.f, 0, 0);
  gemm<<<dim3(4, 16), 256, 0, stream>>>(W + OFF_TMP, 512, (const float*)d_in[18], 512,
      W + OFF_ATTN, 256, 0, 512, nullptr, nullptr, 0.04419417382415922f, F_SCALE, 0);
  softmax_kernel<<<1024, 256, 0, stream>>>(W + OFF_ATTN);
  gemm<<<dim3(8, 16), 256, 0, stream>>>(W + OFF_ATTN, 256, (const float*)d_in[18], 512,
      W + OFF_COMB, 2048, 1536, 256, nullptr, nullptr, 1.f, F_NN, 0);

  // axon + LN -> thought directly into out (fp32)
  gemm<<<dim3(8, 16), 256, 0, stream>>>(W + OFF_COMB, 2048, (const float*)d_in[21], 2048,
      W + OFF_TMP, 512, 0, 2048, (const float*)d_in[22], nullptr, 1.f, 0, 0);
  ln_kernel<<<1024, 256, 0, stream>>>(W + OFF_TMP, outf + 262144, 512, 0,
      (const float*)d_in[23], (const float*)d_in[24], 1);

  // logits = (thought @ sw^T) * 16 -> out (fp32)
  swnorm_kernel<<<256, 256, 0, stream>>>(soma, W + OFF_SW);
  gemm<<<dim3(4, 16), 256, 0, stream>>>(outf + 262144, 512, W + OFF_SW, 512,
      outf, 256, 0, 512, nullptr, nullptr, 16.f, F_SCALE, 0);
}